// Round 3
// baseline (1113.773 us; speedup 1.0000x reference)
//
#include <hip/hip_runtime.h>
#include <cfloat>

#define BATCH 4
#define P 8192
#define C 64
#define KNN 16
#define NPTS (BATCH * P)        // 32768
#define NEDGE (NPTS * KNN)      // 524288
#define EPSV 1e-5f
#define SLOPE 0.2f
#define CAP 16
#define NQ 4                    // column-range split per row-tile
#define QCOLS (P / NQ)          // 2048 cols per block

typedef __attribute__((ext_vector_type(8))) short bf16x8;
typedef __attribute__((ext_vector_type(16))) float f32x16;

// ---------------- workspace layout (float element offsets) ----------------
// U      : [NPTS][C]   @ 0          (2097152)   written AFTER knn
// V      : [NPTS][C]   @ 2097152    (2097152)   written AFTER knn
// xfh/xfm/xfl bf16 frags alias U/V region (dead after knn)
// sq     : [NPTS]      @ 4194304    (32768)
// stats  : [128]       @ 4227072
// sshift : [128]       @ 4227200
// idx    : int[NEDGE]  @ 4227328    (524288)
// pv     : [NPTS][NQ][16] float @ 4751616 (2097152)
// pi     : [NPTS][NQ][16] int   @ 6848768 (2097152)
// total = 8945920 floats = 34.1 MB

__device__ __forceinline__ unsigned short f2bf(float f) {
    unsigned u = __float_as_uint(f);
    u += 0x7FFFu + ((u >> 16) & 1u);
    return (unsigned short)(u >> 16);
}
__device__ __forceinline__ float bf2f(unsigned short s) {
    return __uint_as_float(((unsigned)s) << 16);
}

// ---------------------------------------------------------------------------
// K0: fragment-layout 3-way bf16 split of x + exact fp32 row norms.
// xf[(g*4+kk)*64 + lane] (uint4 = 8 bf16) holds point g*32+(lane&31),
// k = kk*16 + (lane>>5)*8 .. +8  — the mfma_f32_32x32x16_bf16 operand map.
// ---------------------------------------------------------------------------
__global__ void prep_frag(const float* __restrict__ x, uint4* __restrict__ xfh,
                          uint4* __restrict__ xfm, uint4* __restrict__ xfl,
                          float* __restrict__ sq) {
    __shared__ float part[32][9];
    int tid = threadIdx.x;
    int ptl = tid >> 3, j8 = tid & 7;
    int g = blockIdx.x;
    int p = g * 32 + ptl;
    const float4* xp = (const float4*)(x + (size_t)p * C + j8 * 8);
    float4 a = xp[0], b = xp[1];
    float v[8] = {a.x, a.y, a.z, a.w, b.x, b.y, b.z, b.w};
    unsigned short hs[8], ms[8], ls[8];
    float ssum = 0.f;
#pragma unroll
    for (int e = 0; e < 8; ++e) {
        float xv = v[e];
        ssum = fmaf(xv, xv, ssum);
        unsigned short h = f2bf(xv);
        float r1 = xv - bf2f(h);
        unsigned short m = f2bf(r1);
        float r2 = r1 - bf2f(m);
        unsigned short l = f2bf(r2);
        hs[e] = h; ms[e] = m; ls[e] = l;
    }
    int dst = (g * 4 + (j8 >> 1)) * 64 + ptl + 32 * (j8 & 1);
    uint4 ph, pm, pl;
    ph.x = (unsigned)hs[0] | ((unsigned)hs[1] << 16);
    ph.y = (unsigned)hs[2] | ((unsigned)hs[3] << 16);
    ph.z = (unsigned)hs[4] | ((unsigned)hs[5] << 16);
    ph.w = (unsigned)hs[6] | ((unsigned)hs[7] << 16);
    pm.x = (unsigned)ms[0] | ((unsigned)ms[1] << 16);
    pm.y = (unsigned)ms[2] | ((unsigned)ms[3] << 16);
    pm.z = (unsigned)ms[4] | ((unsigned)ms[5] << 16);
    pm.w = (unsigned)ms[6] | ((unsigned)ms[7] << 16);
    pl.x = (unsigned)ls[0] | ((unsigned)ls[1] << 16);
    pl.y = (unsigned)ls[2] | ((unsigned)ls[3] << 16);
    pl.z = (unsigned)ls[4] | ((unsigned)ls[5] << 16);
    pl.w = (unsigned)ls[6] | ((unsigned)ls[7] << 16);
    xfh[dst] = ph; xfm[dst] = pm; xfl[dst] = pl;
    part[ptl][j8] = ssum;
    __syncthreads();
    if (j8 == 0) {
        float s = 0.f;
#pragma unroll
        for (int k = 0; k < 8; ++k) s += part[ptl][k];
        sq[p] = s;
    }
}

// ---------------------------------------------------------------------------
// top-16-smallest register list maintenance (replace-max)
// ---------------------------------------------------------------------------
__device__ __forceinline__ void tk_insert(float (&v)[16], int (&id)[16],
                                          float& worst, float s, int cand) {
    if (s < worst) {
        float w = v[0];
        int pos = 0;
#pragma unroll
        for (int j = 1; j < 16; ++j) {
            bool g = v[j] > w;
            w = g ? v[j] : w;
            pos = g ? j : pos;
        }
#pragma unroll
        for (int j = 0; j < 16; ++j) {
            if (j == pos) { v[j] = s; id[j] = cand; }
        }
        float nw = v[0];
#pragma unroll
        for (int j = 1; j < 16; ++j) nw = fmaxf(nw, v[j]);
        worst = nw;
    }
}

// ---------------------------------------------------------------------------
// K1: KNN partial. WG = (batch, 64-row tile, column quarter).
// Each block scans its 2048-col quarter, emits partial top-16 per row.
// Grid 2048 -> up to 6 blocks/CU resident (LDS 26KB, VGPR<=85).
// ---------------------------------------------------------------------------
__global__ __launch_bounds__(256, 6) void knn_kernel(const uint4* __restrict__ xfh,
                                                     const uint4* __restrict__ xfm,
                                                     const uint4* __restrict__ xfl,
                                                     const float* __restrict__ sq,
                                                     float* __restrict__ pv,
                                                     int* __restrict__ pi) {
    __shared__ float scoresL[64 * 65];
    __shared__ float bufv[64 * 17];
    __shared__ int   bufi[64 * 17];
    __shared__ int   cntL[64];
    __shared__ float worstL[64];

    int tid = threadIdx.x;
    int b = blockIdx.x & 3;              // batch -> XCDs {b, b+4}: frags L2-resident
    int t = blockIdx.x >> 2;
    int tile = t & 127;
    int quarter = t >> 7;
    int bglob = b * P;
    int r0 = tile * 64;
    int colbase = quarter * QCOLS;
    int w = tid >> 6, lane = tid & 63;
    int wr = w & 1, wc = w >> 1;

    if (tid < 64) { cntL[tid] = 0; worstL[tid] = FLT_MAX; }

    // persistent A fragments for this wave's 32 rows
    int gA = ((bglob + r0) >> 5) + wr;
    bf16x8 Ah[4], Am[4], Al[4];
#pragma unroll
    for (int kk = 0; kk < 4; ++kk) {
        Ah[kk] = __builtin_bit_cast(bf16x8, xfh[(gA * 4 + kk) * 64 + lane]);
        Am[kk] = __builtin_bit_cast(bf16x8, xfm[(gA * 4 + kk) * 64 + lane]);
        Al[kk] = __builtin_bit_cast(bf16x8, xfl[(gA * 4 + kk) * 64 + lane]);
    }

    float tv[16];
    int ti[16];
    float worst = FLT_MAX;
#pragma unroll
    for (int j = 0; j < 16; ++j) { tv[j] = FLT_MAX; ti[j] = 0; }
    int rown = ((lane & 15) << 2) | w;
    bool owner = (lane < 16);

    int selr = tid & 63;
    int selq = tid >> 6;

    for (int chunk = 0; chunk < QCOLS / 64; ++chunk) {
        int c0 = colbase + chunk * 64;
        int gB = ((bglob + c0) >> 5) + wc;
        bf16x8 Bh[4], Bm[4], Bl[4];
#pragma unroll
        for (int kk = 0; kk < 4; ++kk) {
            Bh[kk] = __builtin_bit_cast(bf16x8, xfh[(gB * 4 + kk) * 64 + lane]);
            Bm[kk] = __builtin_bit_cast(bf16x8, xfm[(gB * 4 + kk) * 64 + lane]);
            Bl[kk] = __builtin_bit_cast(bf16x8, xfl[(gB * 4 + kk) * 64 + lane]);
        }
        float sc = sq[bglob + c0 + wc * 32 + (lane & 31)];

        f32x16 acc0, acc1;
#pragma unroll
        for (int i = 0; i < 16; ++i) { acc0[i] = 0.f; acc1[i] = 0.f; }
#pragma unroll
        for (int kk = 0; kk < 4; ++kk) {
            acc0 = __builtin_amdgcn_mfma_f32_32x32x16_bf16(Ah[kk], Bh[kk], acc0, 0, 0, 0);
            acc1 = __builtin_amdgcn_mfma_f32_32x32x16_bf16(Ah[kk], Bm[kk], acc1, 0, 0, 0);
            acc0 = __builtin_amdgcn_mfma_f32_32x32x16_bf16(Am[kk], Bh[kk], acc0, 0, 0, 0);
            acc1 = __builtin_amdgcn_mfma_f32_32x32x16_bf16(Am[kk], Bm[kk], acc1, 0, 0, 0);
            acc0 = __builtin_amdgcn_mfma_f32_32x32x16_bf16(Ah[kk], Bl[kk], acc0, 0, 0, 0);
            acc1 = __builtin_amdgcn_mfma_f32_32x32x16_bf16(Al[kk], Bh[kk], acc1, 0, 0, 0);
        }

        __syncthreads();  // (1) prev merge done -> scoresL reusable
        {
            int colL = wc * 32 + (lane & 31);
            int rbase = wr * 32 + 4 * (lane >> 5);
#pragma unroll
            for (int reg = 0; reg < 16; ++reg) {
                int row = rbase + (reg & 3) + 8 * (reg >> 2);
                scoresL[row * 65 + colL] = fmaf(-2.f, acc0[reg] + acc1[reg], sc);
            }
        }
        __syncthreads();  // (2) scores visible
        {
            float wst = worstL[selr];
#pragma unroll
            for (int j = 0; j < 16; ++j) {
                float s = scoresL[selr * 65 + selq * 16 + j];
                if (s < wst) {
                    int slot = atomicAdd(&cntL[selr], 1);
                    if (slot < CAP) {
                        bufv[selr * 17 + slot] = s;
                        bufi[selr * 17 + slot] = c0 + selq * 16 + j;
                    }
                }
            }
        }
        __syncthreads();  // (3) appends visible
        if (owner) {
            int n = cntL[rown];
            if (n > 0) {
                if (n > CAP) {   // overflow (chunk 0 of each block): rescan row
                    for (int e = 0; e < 64; ++e)
                        tk_insert(tv, ti, worst, scoresL[rown * 65 + e], c0 + e);
                } else {
                    for (int k = 0; k < n; ++k)
                        tk_insert(tv, ti, worst, bufv[rown * 17 + k], bufi[rown * 17 + k]);
                }
                cntL[rown] = 0;
                worstL[rown] = worst;
            }
        }
    }

    if (owner) {
        size_t o = (((size_t)(bglob + r0 + rown)) * NQ + quarter) * KNN;
#pragma unroll
        for (int j = 0; j < 16; ++j) {
            pv[o + j] = tv[j];
            pi[o + j] = bglob + ti[j];
        }
    }
}

// ---------------------------------------------------------------------------
// K1b: merge NQ partial top-16 lists per row -> final idx.
// 256 threads = 64 rows x 4 quarters per block.
// ---------------------------------------------------------------------------
__global__ void merge_kernel(const float* __restrict__ pv, const int* __restrict__ pi,
                             int* __restrict__ idx_out) {
    __shared__ float mv[64][65];
    __shared__ int   mi[64][65];
    int tid = threadIdx.x;
    int lr = tid & 63, q = tid >> 6;
    int row = blockIdx.x * 64 + lr;
    size_t o = ((size_t)row * NQ + q) * KNN;
#pragma unroll
    for (int j = 0; j < 16; ++j) {
        mv[lr][q * 16 + j] = pv[o + j];
        mi[lr][q * 16 + j] = pi[o + j];
    }
    __syncthreads();
    if (tid < 64) {
        float tv[16];
        int ti[16];
        float worst = FLT_MAX;
#pragma unroll
        for (int j = 0; j < 16; ++j) { tv[j] = FLT_MAX; ti[j] = 0; }
        for (int e = 0; e < 64; ++e)
            tk_insert(tv, ti, worst, mv[tid][e], mi[tid][e]);
        size_t oo = (size_t)row * KNN;
#pragma unroll
        for (int j = 0; j < 16; ++j) idx_out[oo + j] = ti[j];
    }
}

// ---------------------------------------------------------------------------
// K2: U = x @ (W1 - W2), V = x @ W2
// ---------------------------------------------------------------------------
__global__ void prep_UV(const float* __restrict__ x, const float* __restrict__ W,
                        float* __restrict__ U, float* __restrict__ V) {
    __shared__ float Ws[128][64];
    __shared__ float xs[4][64];
    int tid = threadIdx.x;
    for (int i = tid; i < 128 * 64; i += 256) ((float*)Ws)[i] = W[i];
    int p0 = blockIdx.x * 4;
    int r = tid >> 6, c = tid & 63;
    xs[r][c] = x[(size_t)(p0 + r) * C + c];
    __syncthreads();
    float u = 0.f, v = 0.f;
#pragma unroll
    for (int k = 0; k < 64; ++k) {
        float xv = xs[r][k];
        float w1 = Ws[k][c];
        float w2 = Ws[64 + k][c];
        u = fmaf(xv, w1 - w2, u);
        v = fmaf(xv, w2, v);
    }
    size_t o = (size_t)(p0 + r) * C + c;
    U[o] = u;
    V[o] = v;
}

// ---------------------------------------------------------------------------
// K3: BN stats
// ---------------------------------------------------------------------------
__global__ void stats_kernel(const float* __restrict__ U, const float* __restrict__ V,
                             const float* __restrict__ bias, const int* __restrict__ idx,
                             float* __restrict__ stats) {
    int tid = threadIdx.x;
    int c = tid & 63, kk = tid >> 6;
    int p0 = blockIdx.x * 32;
    float bc = bias[c];
    float sum = 0.f, sumsq = 0.f;
    for (int pp = 0; pp < 32; ++pp) {
        int p = p0 + pp;
        float u = U[(size_t)p * C + c] + bc;
#pragma unroll
        for (int k4 = 0; k4 < 4; ++k4) {
            int j = idx[(size_t)p * KNN + kk * 4 + k4];
            float h = u + V[(size_t)j * C + c];
            sum += h;
            sumsq = fmaf(h, h, sumsq);
        }
    }
    __shared__ float red[2][4][64];
    red[0][kk][c] = sum;
    red[1][kk][c] = sumsq;
    __syncthreads();
    if (tid < 64) {
        float s = red[0][0][tid] + red[0][1][tid] + red[0][2][tid] + red[0][3][tid];
        atomicAdd(&stats[tid], s);
    } else if (tid < 128) {
        int cc = tid - 64;
        float s = red[1][0][cc] + red[1][1][cc] + red[1][2][cc] + red[1][3][cc];
        atomicAdd(&stats[64 + cc], s);
    }
}

__global__ void finalize_kernel(const float* __restrict__ stats,
                                const float* __restrict__ gamma,
                                const float* __restrict__ beta,
                                float* __restrict__ sshift) {
    int c = threadIdx.x;
    const float N = (float)NEDGE;
    float mean = stats[c] / N;
    float var = stats[64 + c] / N - mean * mean;
    float s = gamma[c] * rsqrtf(var + EPSV);
    sshift[c] = s;
    sshift[64 + c] = beta[c] - mean * s;
}

// ---------------------------------------------------------------------------
// K5: out = lrelu(s*(U+b + max/min_k V[idx]) + t)  (monotone fusion of max_k)
// ---------------------------------------------------------------------------
__global__ void out_kernel(const float* __restrict__ U, const float* __restrict__ V,
                           const float* __restrict__ bias, const int* __restrict__ idx,
                           const float* __restrict__ sshift, float* __restrict__ out) {
    int tid = threadIdx.x;
    int c = tid & 63, g = tid >> 6;
    int p0 = blockIdx.x * 16;
    float s = sshift[c], t = sshift[64 + c];
    float bc = bias[c];
    for (int pp = g; pp < 16; pp += 4) {
        int p = p0 + pp;
        float mx = -FLT_MAX, mn = FLT_MAX;
#pragma unroll
        for (int k = 0; k < KNN; ++k) {
            int j = idx[(size_t)p * KNN + k];
            float v = V[(size_t)j * C + c];
            mx = fmaxf(mx, v);
            mn = fminf(mn, v);
        }
        float hsel = (s >= 0.f) ? mx : mn;
        float hn = fmaf(s, U[(size_t)p * C + c] + bc + hsel, t);
        out[(size_t)p * C + c] = (hn >= 0.f) ? hn : SLOPE * hn;
    }
}

// ---------------------------------------------------------------------------
extern "C" void kernel_launch(void* const* d_in, const int* in_sizes, int n_in,
                              void* d_out, int out_size, void* d_ws, size_t ws_size,
                              hipStream_t stream) {
    const float* x     = (const float*)d_in[0];
    const float* W     = (const float*)d_in[2];
    const float* bias  = (const float*)d_in[3];
    const float* gamma = (const float*)d_in[4];
    const float* beta  = (const float*)d_in[5];
    float* out = (float*)d_out;

    float* wsf    = (float*)d_ws;
    float* U      = wsf;
    float* V      = wsf + 2097152;
    uint4* xfh    = (uint4*)wsf;                   // aliases U/V, dead after knn
    uint4* xfm    = (uint4*)(wsf + 1048576);
    uint4* xfl    = (uint4*)(wsf + 2097152);
    float* sq     = wsf + 4194304;
    float* stats  = wsf + 4227072;
    float* sshift = wsf + 4227200;
    int*   idx    = (int*)(wsf + 4227328);
    float* pv     = wsf + 4751616;
    int*   pi     = (int*)(wsf + 6848768);

    hipLaunchKernelGGL(prep_frag, dim3(NPTS / 32), dim3(256), 0, stream, x, xfh, xfm, xfl, sq);
    hipLaunchKernelGGL(knn_kernel, dim3(BATCH * (P / 64) * NQ), dim3(256), 0, stream,
                       (const uint4*)xfh, (const uint4*)xfm, (const uint4*)xfl, sq, pv, pi);
    hipLaunchKernelGGL(merge_kernel, dim3(NPTS / 64), dim3(256), 0, stream, pv, pi, idx);
    hipLaunchKernelGGL(prep_UV, dim3(NPTS / 4), dim3(256), 0, stream, x, W, U, V);
    hipMemsetAsync(stats, 0, 128 * sizeof(float), stream);
    hipLaunchKernelGGL(stats_kernel, dim3(NPTS / 32), dim3(256), 0, stream, U, V, bias, idx, stats);
    hipLaunchKernelGGL(finalize_kernel, dim3(1), dim3(64), 0, stream, stats, gamma, beta, sshift);
    hipLaunchKernelGGL(out_kernel, dim3(NPTS / 16), dim3(256), 0, stream, U, V, bias, idx, sshift, out);
}

// Round 4
// 756.109 us; speedup vs baseline: 1.4730x; 1.4730x over previous
//
#include <hip/hip_runtime.h>
#include <cfloat>

#define BATCH 4
#define P 8192
#define C 64
#define KNN 16
#define NPTS (BATCH * P)        // 32768
#define NEDGE (NPTS * KNN)      // 524288
#define EPSV 1e-5f
#define SLOPE 0.2f
#define CAP 16
#define NQ 4                    // column-range split per row-tile
#define QCOLS (P / NQ)          // 2048 cols per block

typedef __attribute__((ext_vector_type(8))) short bf16x8;
typedef __attribute__((ext_vector_type(16))) float f32x16;

// ---------------- workspace layout (float element offsets) ----------------
// U      : [NPTS][C]   @ 0          (2097152)   written AFTER knn
// V      : [NPTS][C]   @ 2097152    (2097152)   written AFTER knn
// xfh/xfm/xfl bf16 frags alias U/V region (dead after knn)
// sq     : [NPTS]      @ 4194304    (32768)
// stats  : [128]       @ 4227072
// sshift : [128]       @ 4227200
// idx    : int[NEDGE]  @ 4227328    (524288)
// pv     : [NPTS][NQ][16] float @ 4751616 (2097152)
// pi     : [NPTS][NQ][16] int   @ 6848768 (2097152)
// total = 8945920 floats = 34.1 MB

__device__ __forceinline__ unsigned short f2bf(float f) {
    unsigned u = __float_as_uint(f);
    u += 0x7FFFu + ((u >> 16) & 1u);
    return (unsigned short)(u >> 16);
}
__device__ __forceinline__ float bf2f(unsigned short s) {
    return __uint_as_float(((unsigned)s) << 16);
}

// ---------------------------------------------------------------------------
// K0: fragment-layout 3-way bf16 split of x + exact fp32 row norms.
// xf[(g*4+kk)*64 + lane] (uint4 = 8 bf16) holds point g*32+(lane&31),
// k = kk*16 + (lane>>5)*8 .. +8  — the mfma_f32_32x32x16_bf16 operand map.
// ---------------------------------------------------------------------------
__global__ void prep_frag(const float* __restrict__ x, uint4* __restrict__ xfh,
                          uint4* __restrict__ xfm, uint4* __restrict__ xfl,
                          float* __restrict__ sq) {
    __shared__ float part[32][9];
    int tid = threadIdx.x;
    int ptl = tid >> 3, j8 = tid & 7;
    int g = blockIdx.x;
    int p = g * 32 + ptl;
    const float4* xp = (const float4*)(x + (size_t)p * C + j8 * 8);
    float4 a = xp[0], b = xp[1];
    float v[8] = {a.x, a.y, a.z, a.w, b.x, b.y, b.z, b.w};
    unsigned short hs[8], ms[8], ls[8];
    float ssum = 0.f;
#pragma unroll
    for (int e = 0; e < 8; ++e) {
        float xv = v[e];
        ssum = fmaf(xv, xv, ssum);
        unsigned short h = f2bf(xv);
        float r1 = xv - bf2f(h);
        unsigned short m = f2bf(r1);
        float r2 = r1 - bf2f(m);
        unsigned short l = f2bf(r2);
        hs[e] = h; ms[e] = m; ls[e] = l;
    }
    int dst = (g * 4 + (j8 >> 1)) * 64 + ptl + 32 * (j8 & 1);
    uint4 ph, pm, pl;
    ph.x = (unsigned)hs[0] | ((unsigned)hs[1] << 16);
    ph.y = (unsigned)hs[2] | ((unsigned)hs[3] << 16);
    ph.z = (unsigned)hs[4] | ((unsigned)hs[5] << 16);
    ph.w = (unsigned)hs[6] | ((unsigned)hs[7] << 16);
    pm.x = (unsigned)ms[0] | ((unsigned)ms[1] << 16);
    pm.y = (unsigned)ms[2] | ((unsigned)ms[3] << 16);
    pm.z = (unsigned)ms[4] | ((unsigned)ms[5] << 16);
    pm.w = (unsigned)ms[6] | ((unsigned)ms[7] << 16);
    pl.x = (unsigned)ls[0] | ((unsigned)ls[1] << 16);
    pl.y = (unsigned)ls[2] | ((unsigned)ls[3] << 16);
    pl.z = (unsigned)ls[4] | ((unsigned)ls[5] << 16);
    pl.w = (unsigned)ls[6] | ((unsigned)ls[7] << 16);
    xfh[dst] = ph; xfm[dst] = pm; xfl[dst] = pl;
    part[ptl][j8] = ssum;
    __syncthreads();
    if (j8 == 0) {
        float s = 0.f;
#pragma unroll
        for (int k = 0; k < 8; ++k) s += part[ptl][k];
        sq[p] = s;
    }
}

// ---------------------------------------------------------------------------
// top-16-smallest register list maintenance (replace-max)
// ---------------------------------------------------------------------------
__device__ __forceinline__ void tk_insert(float (&v)[16], int (&id)[16],
                                          float& worst, float s, int cand) {
    if (s < worst) {
        float w = v[0];
        int pos = 0;
#pragma unroll
        for (int j = 1; j < 16; ++j) {
            bool g = v[j] > w;
            w = g ? v[j] : w;
            pos = g ? j : pos;
        }
#pragma unroll
        for (int j = 0; j < 16; ++j) {
            if (j == pos) { v[j] = s; id[j] = cand; }
        }
        float nw = v[0];
#pragma unroll
        for (int j = 1; j < 16; ++j) nw = fmaxf(nw, v[j]);
        worst = nw;
    }
}

// ---------------------------------------------------------------------------
// K1: KNN partial. WG = (batch, 64-row tile, column quarter).
// Each block scans its 2048-col quarter, emits partial top-16 per row.
// __launch_bounds__(256,4): VGPR cap 128 — kernel needs ~80 live
// (A-frags 48 + acc 32). (256,6) forced 40 VGPR -> scratch spills,
// FETCH 2 GB/dispatch, 2x slower (round-3 lesson). 4 blocks/CU resident.
// ---------------------------------------------------------------------------
__global__ __launch_bounds__(256, 4) void knn_kernel(const uint4* __restrict__ xfh,
                                                     const uint4* __restrict__ xfm,
                                                     const uint4* __restrict__ xfl,
                                                     const float* __restrict__ sq,
                                                     float* __restrict__ pv,
                                                     int* __restrict__ pi) {
    __shared__ float scoresL[64 * 65];
    __shared__ float bufv[64 * 17];
    __shared__ int   bufi[64 * 17];
    __shared__ int   cntL[64];
    __shared__ float worstL[64];

    int tid = threadIdx.x;
    int b = blockIdx.x & 3;              // batch -> XCDs {b, b+4}: frags L2-resident
    int t = blockIdx.x >> 2;
    int tile = t & 127;
    int quarter = t >> 7;
    int bglob = b * P;
    int r0 = tile * 64;
    int colbase = quarter * QCOLS;
    int w = tid >> 6, lane = tid & 63;
    int wr = w & 1, wc = w >> 1;

    if (tid < 64) { cntL[tid] = 0; worstL[tid] = FLT_MAX; }

    // persistent A fragments for this wave's 32 rows
    int gA = ((bglob + r0) >> 5) + wr;
    bf16x8 Ah[4], Am[4], Al[4];
#pragma unroll
    for (int kk = 0; kk < 4; ++kk) {
        Ah[kk] = __builtin_bit_cast(bf16x8, xfh[(gA * 4 + kk) * 64 + lane]);
        Am[kk] = __builtin_bit_cast(bf16x8, xfm[(gA * 4 + kk) * 64 + lane]);
        Al[kk] = __builtin_bit_cast(bf16x8, xfl[(gA * 4 + kk) * 64 + lane]);
    }

    float tv[16];
    int ti[16];
    float worst = FLT_MAX;
#pragma unroll
    for (int j = 0; j < 16; ++j) { tv[j] = FLT_MAX; ti[j] = 0; }
    int rown = ((lane & 15) << 2) | w;
    bool owner = (lane < 16);

    int selr = tid & 63;
    int selq = tid >> 6;

    for (int chunk = 0; chunk < QCOLS / 64; ++chunk) {
        int c0 = colbase + chunk * 64;
        int gB = ((bglob + c0) >> 5) + wc;
        bf16x8 Bh[4], Bm[4], Bl[4];
#pragma unroll
        for (int kk = 0; kk < 4; ++kk) {
            Bh[kk] = __builtin_bit_cast(bf16x8, xfh[(gB * 4 + kk) * 64 + lane]);
            Bm[kk] = __builtin_bit_cast(bf16x8, xfm[(gB * 4 + kk) * 64 + lane]);
            Bl[kk] = __builtin_bit_cast(bf16x8, xfl[(gB * 4 + kk) * 64 + lane]);
        }
        float sc = sq[bglob + c0 + wc * 32 + (lane & 31)];

        f32x16 acc0, acc1;
#pragma unroll
        for (int i = 0; i < 16; ++i) { acc0[i] = 0.f; acc1[i] = 0.f; }
#pragma unroll
        for (int kk = 0; kk < 4; ++kk) {
            acc0 = __builtin_amdgcn_mfma_f32_32x32x16_bf16(Ah[kk], Bh[kk], acc0, 0, 0, 0);
            acc1 = __builtin_amdgcn_mfma_f32_32x32x16_bf16(Ah[kk], Bm[kk], acc1, 0, 0, 0);
            acc0 = __builtin_amdgcn_mfma_f32_32x32x16_bf16(Am[kk], Bh[kk], acc0, 0, 0, 0);
            acc1 = __builtin_amdgcn_mfma_f32_32x32x16_bf16(Am[kk], Bm[kk], acc1, 0, 0, 0);
            acc0 = __builtin_amdgcn_mfma_f32_32x32x16_bf16(Ah[kk], Bl[kk], acc0, 0, 0, 0);
            acc1 = __builtin_amdgcn_mfma_f32_32x32x16_bf16(Al[kk], Bh[kk], acc1, 0, 0, 0);
        }

        __syncthreads();  // (1) prev merge done -> scoresL reusable
        {
            int colL = wc * 32 + (lane & 31);
            int rbase = wr * 32 + 4 * (lane >> 5);
#pragma unroll
            for (int reg = 0; reg < 16; ++reg) {
                int row = rbase + (reg & 3) + 8 * (reg >> 2);
                scoresL[row * 65 + colL] = fmaf(-2.f, acc0[reg] + acc1[reg], sc);
            }
        }
        __syncthreads();  // (2) scores visible
        {
            float wst = worstL[selr];
#pragma unroll
            for (int j = 0; j < 16; ++j) {
                float s = scoresL[selr * 65 + selq * 16 + j];
                if (s < wst) {
                    int slot = atomicAdd(&cntL[selr], 1);
                    if (slot < CAP) {
                        bufv[selr * 17 + slot] = s;
                        bufi[selr * 17 + slot] = c0 + selq * 16 + j;
                    }
                }
            }
        }
        __syncthreads();  // (3) appends visible
        if (owner) {
            int n = cntL[rown];
            if (n > 0) {
                if (n > CAP) {   // overflow (chunk 0 of each block): rescan row
                    for (int e = 0; e < 64; ++e)
                        tk_insert(tv, ti, worst, scoresL[rown * 65 + e], c0 + e);
                } else {
                    for (int k = 0; k < n; ++k)
                        tk_insert(tv, ti, worst, bufv[rown * 17 + k], bufi[rown * 17 + k]);
                }
                cntL[rown] = 0;
                worstL[rown] = worst;
            }
        }
    }

    if (owner) {
        size_t o = (((size_t)(bglob + r0 + rown)) * NQ + quarter) * KNN;
#pragma unroll
        for (int j = 0; j < 16; ++j) {
            pv[o + j] = tv[j];
            pi[o + j] = bglob + ti[j];
        }
    }
}

// ---------------------------------------------------------------------------
// K1b: merge NQ partial top-16 lists per row -> final idx.
// ---------------------------------------------------------------------------
__global__ void merge_kernel(const float* __restrict__ pv, const int* __restrict__ pi,
                             int* __restrict__ idx_out) {
    __shared__ float mv[64][65];
    __shared__ int   mi[64][65];
    int tid = threadIdx.x;
    int lr = tid & 63, q = tid >> 6;
    int row = blockIdx.x * 64 + lr;
    size_t o = ((size_t)row * NQ + q) * KNN;
#pragma unroll
    for (int j = 0; j < 16; ++j) {
        mv[lr][q * 16 + j] = pv[o + j];
        mi[lr][q * 16 + j] = pi[o + j];
    }
    __syncthreads();
    if (tid < 64) {
        float tv[16];
        int ti[16];
        float worst = FLT_MAX;
#pragma unroll
        for (int j = 0; j < 16; ++j) { tv[j] = FLT_MAX; ti[j] = 0; }
        for (int e = 0; e < 64; ++e)
            tk_insert(tv, ti, worst, mv[tid][e], mi[tid][e]);
        size_t oo = (size_t)row * KNN;
#pragma unroll
        for (int j = 0; j < 16; ++j) idx_out[oo + j] = ti[j];
    }
}

// ---------------------------------------------------------------------------
// K2: U = x @ (W1 - W2), V = x @ W2
// ---------------------------------------------------------------------------
__global__ void prep_UV(const float* __restrict__ x, const float* __restrict__ W,
                        float* __restrict__ U, float* __restrict__ V) {
    __shared__ float Ws[128][64];
    __shared__ float xs[4][64];
    int tid = threadIdx.x;
    for (int i = tid; i < 128 * 64; i += 256) ((float*)Ws)[i] = W[i];
    int p0 = blockIdx.x * 4;
    int r = tid >> 6, c = tid & 63;
    xs[r][c] = x[(size_t)(p0 + r) * C + c];
    __syncthreads();
    float u = 0.f, v = 0.f;
#pragma unroll
    for (int k = 0; k < 64; ++k) {
        float xv = xs[r][k];
        float w1 = Ws[k][c];
        float w2 = Ws[64 + k][c];
        u = fmaf(xv, w1 - w2, u);
        v = fmaf(xv, w2, v);
    }
    size_t o = (size_t)(p0 + r) * C + c;
    U[o] = u;
    V[o] = v;
}

// ---------------------------------------------------------------------------
// K3: BN stats
// ---------------------------------------------------------------------------
__global__ void stats_kernel(const float* __restrict__ U, const float* __restrict__ V,
                             const float* __restrict__ bias, const int* __restrict__ idx,
                             float* __restrict__ stats) {
    int tid = threadIdx.x;
    int c = tid & 63, kk = tid >> 6;
    int p0 = blockIdx.x * 32;
    float bc = bias[c];
    float sum = 0.f, sumsq = 0.f;
    for (int pp = 0; pp < 32; ++pp) {
        int p = p0 + pp;
        float u = U[(size_t)p * C + c] + bc;
#pragma unroll
        for (int k4 = 0; k4 < 4; ++k4) {
            int j = idx[(size_t)p * KNN + kk * 4 + k4];
            float h = u + V[(size_t)j * C + c];
            sum += h;
            sumsq = fmaf(h, h, sumsq);
        }
    }
    __shared__ float red[2][4][64];
    red[0][kk][c] = sum;
    red[1][kk][c] = sumsq;
    __syncthreads();
    if (tid < 64) {
        float s = red[0][0][tid] + red[0][1][tid] + red[0][2][tid] + red[0][3][tid];
        atomicAdd(&stats[tid], s);
    } else if (tid < 128) {
        int cc = tid - 64;
        float s = red[1][0][cc] + red[1][1][cc] + red[1][2][cc] + red[1][3][cc];
        atomicAdd(&stats[64 + cc], s);
    }
}

__global__ void finalize_kernel(const float* __restrict__ stats,
                                const float* __restrict__ gamma,
                                const float* __restrict__ beta,
                                float* __restrict__ sshift) {
    int c = threadIdx.x;
    const float N = (float)NEDGE;
    float mean = stats[c] / N;
    float var = stats[64 + c] / N - mean * mean;
    float s = gamma[c] * rsqrtf(var + EPSV);
    sshift[c] = s;
    sshift[64 + c] = beta[c] - mean * s;
}

// ---------------------------------------------------------------------------
// K5: out = lrelu(s*(U+b + max/min_k V[idx]) + t)  (monotone fusion of max_k)
// ---------------------------------------------------------------------------
__global__ void out_kernel(const float* __restrict__ U, const float* __restrict__ V,
                           const float* __restrict__ bias, const int* __restrict__ idx,
                           const float* __restrict__ sshift, float* __restrict__ out) {
    int tid = threadIdx.x;
    int c = tid & 63, g = tid >> 6;
    int p0 = blockIdx.x * 16;
    float s = sshift[c], t = sshift[64 + c];
    float bc = bias[c];
    for (int pp = g; pp < 16; pp += 4) {
        int p = p0 + pp;
        float mx = -FLT_MAX, mn = FLT_MAX;
#pragma unroll
        for (int k = 0; k < KNN; ++k) {
            int j = idx[(size_t)p * KNN + k];
            float v = V[(size_t)j * C + c];
            mx = fmaxf(mx, v);
            mn = fminf(mn, v);
        }
        float hsel = (s >= 0.f) ? mx : mn;
        float hn = fmaf(s, U[(size_t)p * C + c] + bc + hsel, t);
        out[(size_t)p * C + c] = (hn >= 0.f) ? hn : SLOPE * hn;
    }
}

// ---------------------------------------------------------------------------
extern "C" void kernel_launch(void* const* d_in, const int* in_sizes, int n_in,
                              void* d_out, int out_size, void* d_ws, size_t ws_size,
                              hipStream_t stream) {
    const float* x     = (const float*)d_in[0];
    const float* W     = (const float*)d_in[2];
    const float* bias  = (const float*)d_in[3];
    const float* gamma = (const float*)d_in[4];
    const float* beta  = (const float*)d_in[5];
    float* out = (float*)d_out;

    float* wsf    = (float*)d_ws;
    float* U      = wsf;
    float* V      = wsf + 2097152;
    uint4* xfh    = (uint4*)wsf;                   // aliases U/V, dead after knn
    uint4* xfm    = (uint4*)(wsf + 1048576);
    uint4* xfl    = (uint4*)(wsf + 2097152);
    float* sq     = wsf + 4194304;
    float* stats  = wsf + 4227072;
    float* sshift = wsf + 4227200;
    int*   idx    = (int*)(wsf + 4227328);
    float* pv     = wsf + 4751616;
    int*   pi     = (int*)(wsf + 6848768);

    hipLaunchKernelGGL(prep_frag, dim3(NPTS / 32), dim3(256), 0, stream, x, xfh, xfm, xfl, sq);
    hipLaunchKernelGGL(knn_kernel, dim3(BATCH * (P / 64) * NQ), dim3(256), 0, stream,
                       (const uint4*)xfh, (const uint4*)xfm, (const uint4*)xfl, sq, pv, pi);
    hipLaunchKernelGGL(merge_kernel, dim3(NPTS / 64), dim3(256), 0, stream, pv, pi, idx);
    hipLaunchKernelGGL(prep_UV, dim3(NPTS / 4), dim3(256), 0, stream, x, W, U, V);
    hipMemsetAsync(stats, 0, 128 * sizeof(float), stream);
    hipLaunchKernelGGL(stats_kernel, dim3(NPTS / 32), dim3(256), 0, stream, U, V, bias, idx, stats);
    hipLaunchKernelGGL(finalize_kernel, dim3(1), dim3(64), 0, stream, stats, gamma, beta, sshift);
    hipLaunchKernelGGL(out_kernel, dim3(NPTS / 16), dim3(256), 0, stream, U, V, bias, idx, sshift, out);
}

// Round 5
// 748.099 us; speedup vs baseline: 1.4888x; 1.0107x over previous
//
#include <hip/hip_runtime.h>
#include <cfloat>

#define BATCH 4
#define P 8192
#define C 64
#define KNN 16
#define NPTS (BATCH * P)        // 32768
#define NEDGE (NPTS * KNN)      // 524288
#define EPSV 1e-5f
#define SLOPE 0.2f
#define CAP 16
#define NQ 4                    // column-range split per row-tile
#define QCOLS (P / NQ)          // 2048 cols per block

typedef __attribute__((ext_vector_type(8))) short bf16x8;
typedef __attribute__((ext_vector_type(16))) float f32x16;

// ---------------- workspace layout (float element offsets) ----------------
// U      : [NPTS][C]   @ 0          (2097152)   written AFTER knn
// V      : [NPTS][C]   @ 2097152    (2097152)   written AFTER knn
// xfh/xfm/xfl bf16 frags alias U/V region (dead after knn)
// sq     : [NPTS]      @ 4194304    (32768)
// stats  : [128]       @ 4227072
// sshift : [128]       @ 4227200
// idx    : int[NEDGE]  @ 4227328    (524288)
// pv     : [NPTS][NQ][16] float @ 4751616 (2097152)
// pi     : [NPTS][NQ][16] int   @ 6848768 (2097152)
// total = 8945920 floats = 34.1 MB

__device__ __forceinline__ unsigned short f2bf(float f) {
    unsigned u = __float_as_uint(f);
    u += 0x7FFFu + ((u >> 16) & 1u);
    return (unsigned short)(u >> 16);
}
__device__ __forceinline__ float bf2f(unsigned short s) {
    return __uint_as_float(((unsigned)s) << 16);
}

// ---------------------------------------------------------------------------
// K0: fragment-layout 3-way bf16 split of x + exact fp32 row norms.
// xf[(g*4+kk)*64 + lane] (uint4 = 8 bf16) holds point g*32+(lane&31),
// k = kk*16 + (lane>>5)*8 .. +8  — the mfma_f32_32x32x16_bf16 operand map.
// ---------------------------------------------------------------------------
__global__ void prep_frag(const float* __restrict__ x, uint4* __restrict__ xfh,
                          uint4* __restrict__ xfm, uint4* __restrict__ xfl,
                          float* __restrict__ sq) {
    __shared__ float part[32][9];
    int tid = threadIdx.x;
    int ptl = tid >> 3, j8 = tid & 7;
    int g = blockIdx.x;
    int p = g * 32 + ptl;
    const float4* xp = (const float4*)(x + (size_t)p * C + j8 * 8);
    float4 a = xp[0], b = xp[1];
    float v[8] = {a.x, a.y, a.z, a.w, b.x, b.y, b.z, b.w};
    unsigned short hs[8], ms[8], ls[8];
    float ssum = 0.f;
#pragma unroll
    for (int e = 0; e < 8; ++e) {
        float xv = v[e];
        ssum = fmaf(xv, xv, ssum);
        unsigned short h = f2bf(xv);
        float r1 = xv - bf2f(h);
        unsigned short m = f2bf(r1);
        float r2 = r1 - bf2f(m);
        unsigned short l = f2bf(r2);
        hs[e] = h; ms[e] = m; ls[e] = l;
    }
    int dst = (g * 4 + (j8 >> 1)) * 64 + ptl + 32 * (j8 & 1);
    uint4 ph, pm, pl;
    ph.x = (unsigned)hs[0] | ((unsigned)hs[1] << 16);
    ph.y = (unsigned)hs[2] | ((unsigned)hs[3] << 16);
    ph.z = (unsigned)hs[4] | ((unsigned)hs[5] << 16);
    ph.w = (unsigned)hs[6] | ((unsigned)hs[7] << 16);
    pm.x = (unsigned)ms[0] | ((unsigned)ms[1] << 16);
    pm.y = (unsigned)ms[2] | ((unsigned)ms[3] << 16);
    pm.z = (unsigned)ms[4] | ((unsigned)ms[5] << 16);
    pm.w = (unsigned)ms[6] | ((unsigned)ms[7] << 16);
    pl.x = (unsigned)ls[0] | ((unsigned)ls[1] << 16);
    pl.y = (unsigned)ls[2] | ((unsigned)ls[3] << 16);
    pl.z = (unsigned)ls[4] | ((unsigned)ls[5] << 16);
    pl.w = (unsigned)ls[6] | ((unsigned)ls[7] << 16);
    xfh[dst] = ph; xfm[dst] = pm; xfl[dst] = pl;
    part[ptl][j8] = ssum;
    __syncthreads();
    if (j8 == 0) {
        float s = 0.f;
#pragma unroll
        for (int k = 0; k < 8; ++k) s += part[ptl][k];
        sq[p] = s;
    }
}

// ---------------------------------------------------------------------------
// top-16-smallest register list maintenance (replace-max)
// ---------------------------------------------------------------------------
__device__ __forceinline__ void tk_insert(float (&v)[16], int (&id)[16],
                                          float& worst, float s, int cand) {
    if (s < worst) {
        float w = v[0];
        int pos = 0;
#pragma unroll
        for (int j = 1; j < 16; ++j) {
            bool g = v[j] > w;
            w = g ? v[j] : w;
            pos = g ? j : pos;
        }
#pragma unroll
        for (int j = 0; j < 16; ++j) {
            if (j == pos) { v[j] = s; id[j] = cand; }
        }
        float nw = v[0];
#pragma unroll
        for (int j = 1; j < 16; ++j) nw = fmaxf(nw, v[j]);
        worst = nw;
    }
}

// ---------------------------------------------------------------------------
// K1: KNN partial. WG = (batch, 64-row tile, column quarter).
// Each block scans its 2048-col quarter, emits partial top-16 per row.
// __launch_bounds__(256,3): gfx950 VGPR/AGPR file is UNIFIED — per-wave
// budget = 512/waves INCLUDING the 32 AGPR accumulators. Live state:
// A-frags 48 + B-frags ~48 + tv/ti 32 + misc ~20 VGPR + 32 AGPR ≈ 170.
//   (256,6) -> cap 85  -> massive spill (round 3: FETCH 2 GB, 970 us)
//   (256,4) -> cap 128 -> still spills (round 4: WRITE 62 MB, 634 us)
//   (256,3) -> cap 170 -> fits. 3 blocks/CU, no scratch.
// ---------------------------------------------------------------------------
__global__ __launch_bounds__(256, 3) void knn_kernel(const uint4* __restrict__ xfh,
                                                     const uint4* __restrict__ xfm,
                                                     const uint4* __restrict__ xfl,
                                                     const float* __restrict__ sq,
                                                     float* __restrict__ pv,
                                                     int* __restrict__ pi) {
    __shared__ float scoresL[64 * 65];
    __shared__ float bufv[64 * 17];
    __shared__ int   bufi[64 * 17];
    __shared__ int   cntL[64];
    __shared__ float worstL[64];

    int tid = threadIdx.x;
    int b = blockIdx.x & 3;              // batch -> XCDs {b, b+4}: frags L2-resident
    int t = blockIdx.x >> 2;
    int tile = t & 127;
    int quarter = t >> 7;
    int bglob = b * P;
    int r0 = tile * 64;
    int colbase = quarter * QCOLS;
    int w = tid >> 6, lane = tid & 63;
    int wr = w & 1, wc = w >> 1;

    if (tid < 64) { cntL[tid] = 0; worstL[tid] = FLT_MAX; }

    // persistent A fragments for this wave's 32 rows
    int gA = ((bglob + r0) >> 5) + wr;
    bf16x8 Ah[4], Am[4], Al[4];
#pragma unroll
    for (int kk = 0; kk < 4; ++kk) {
        Ah[kk] = __builtin_bit_cast(bf16x8, xfh[(gA * 4 + kk) * 64 + lane]);
        Am[kk] = __builtin_bit_cast(bf16x8, xfm[(gA * 4 + kk) * 64 + lane]);
        Al[kk] = __builtin_bit_cast(bf16x8, xfl[(gA * 4 + kk) * 64 + lane]);
    }

    float tv[16];
    int ti[16];
    float worst = FLT_MAX;
#pragma unroll
    for (int j = 0; j < 16; ++j) { tv[j] = FLT_MAX; ti[j] = 0; }
    int rown = ((lane & 15) << 2) | w;
    bool owner = (lane < 16);

    int selr = tid & 63;
    int selq = tid >> 6;

    for (int chunk = 0; chunk < QCOLS / 64; ++chunk) {
        int c0 = colbase + chunk * 64;
        int gB = ((bglob + c0) >> 5) + wc;
        bf16x8 Bh[4], Bm[4], Bl[4];
#pragma unroll
        for (int kk = 0; kk < 4; ++kk) {
            Bh[kk] = __builtin_bit_cast(bf16x8, xfh[(gB * 4 + kk) * 64 + lane]);
            Bm[kk] = __builtin_bit_cast(bf16x8, xfm[(gB * 4 + kk) * 64 + lane]);
            Bl[kk] = __builtin_bit_cast(bf16x8, xfl[(gB * 4 + kk) * 64 + lane]);
        }
        float sc = sq[bglob + c0 + wc * 32 + (lane & 31)];

        f32x16 acc0, acc1;
#pragma unroll
        for (int i = 0; i < 16; ++i) { acc0[i] = 0.f; acc1[i] = 0.f; }
#pragma unroll
        for (int kk = 0; kk < 4; ++kk) {
            acc0 = __builtin_amdgcn_mfma_f32_32x32x16_bf16(Ah[kk], Bh[kk], acc0, 0, 0, 0);
            acc1 = __builtin_amdgcn_mfma_f32_32x32x16_bf16(Ah[kk], Bm[kk], acc1, 0, 0, 0);
            acc0 = __builtin_amdgcn_mfma_f32_32x32x16_bf16(Am[kk], Bh[kk], acc0, 0, 0, 0);
            acc1 = __builtin_amdgcn_mfma_f32_32x32x16_bf16(Am[kk], Bm[kk], acc1, 0, 0, 0);
            acc0 = __builtin_amdgcn_mfma_f32_32x32x16_bf16(Ah[kk], Bl[kk], acc0, 0, 0, 0);
            acc1 = __builtin_amdgcn_mfma_f32_32x32x16_bf16(Al[kk], Bh[kk], acc1, 0, 0, 0);
        }

        __syncthreads();  // (1) prev merge done -> scoresL reusable
        {
            int colL = wc * 32 + (lane & 31);
            int rbase = wr * 32 + 4 * (lane >> 5);
#pragma unroll
            for (int reg = 0; reg < 16; ++reg) {
                int row = rbase + (reg & 3) + 8 * (reg >> 2);
                scoresL[row * 65 + colL] = fmaf(-2.f, acc0[reg] + acc1[reg], sc);
            }
        }
        __syncthreads();  // (2) scores visible
        {
            float wst = worstL[selr];
#pragma unroll
            for (int j = 0; j < 16; ++j) {
                float s = scoresL[selr * 65 + selq * 16 + j];
                if (s < wst) {
                    int slot = atomicAdd(&cntL[selr], 1);
                    if (slot < CAP) {
                        bufv[selr * 17 + slot] = s;
                        bufi[selr * 17 + slot] = c0 + selq * 16 + j;
                    }
                }
            }
        }
        __syncthreads();  // (3) appends visible
        if (owner) {
            int n = cntL[rown];
            if (n > 0) {
                if (n > CAP) {   // overflow (chunk 0 of each block): rescan row
                    for (int e = 0; e < 64; ++e)
                        tk_insert(tv, ti, worst, scoresL[rown * 65 + e], c0 + e);
                } else {
                    for (int k = 0; k < n; ++k)
                        tk_insert(tv, ti, worst, bufv[rown * 17 + k], bufi[rown * 17 + k]);
                }
                cntL[rown] = 0;
                worstL[rown] = worst;
            }
        }
    }

    if (owner) {
        size_t o = (((size_t)(bglob + r0 + rown)) * NQ + quarter) * KNN;
#pragma unroll
        for (int j = 0; j < 16; ++j) {
            pv[o + j] = tv[j];
            pi[o + j] = bglob + ti[j];
        }
    }
}

// ---------------------------------------------------------------------------
// K1b: merge NQ partial top-16 lists per row -> final idx.
// ---------------------------------------------------------------------------
__global__ void merge_kernel(const float* __restrict__ pv, const int* __restrict__ pi,
                             int* __restrict__ idx_out) {
    __shared__ float mv[64][65];
    __shared__ int   mi[64][65];
    int tid = threadIdx.x;
    int lr = tid & 63, q = tid >> 6;
    int row = blockIdx.x * 64 + lr;
    size_t o = ((size_t)row * NQ + q) * KNN;
#pragma unroll
    for (int j = 0; j < 16; ++j) {
        mv[lr][q * 16 + j] = pv[o + j];
        mi[lr][q * 16 + j] = pi[o + j];
    }
    __syncthreads();
    if (tid < 64) {
        float tv[16];
        int ti[16];
        float worst = FLT_MAX;
#pragma unroll
        for (int j = 0; j < 16; ++j) { tv[j] = FLT_MAX; ti[j] = 0; }
        for (int e = 0; e < 64; ++e)
            tk_insert(tv, ti, worst, mv[tid][e], mi[tid][e]);
        size_t oo = (size_t)row * KNN;
#pragma unroll
        for (int j = 0; j < 16; ++j) idx_out[oo + j] = ti[j];
    }
}

// ---------------------------------------------------------------------------
// K2: U = x @ (W1 - W2), V = x @ W2
// ---------------------------------------------------------------------------
__global__ void prep_UV(const float* __restrict__ x, const float* __restrict__ W,
                        float* __restrict__ U, float* __restrict__ V) {
    __shared__ float Ws[128][64];
    __shared__ float xs[4][64];
    int tid = threadIdx.x;
    for (int i = tid; i < 128 * 64; i += 256) ((float*)Ws)[i] = W[i];
    int p0 = blockIdx.x * 4;
    int r = tid >> 6, c = tid & 63;
    xs[r][c] = x[(size_t)(p0 + r) * C + c];
    __syncthreads();
    float u = 0.f, v = 0.f;
#pragma unroll
    for (int k = 0; k < 64; ++k) {
        float xv = xs[r][k];
        float w1 = Ws[k][c];
        float w2 = Ws[64 + k][c];
        u = fmaf(xv, w1 - w2, u);
        v = fmaf(xv, w2, v);
    }
    size_t o = (size_t)(p0 + r) * C + c;
    U[o] = u;
    V[o] = v;
}

// ---------------------------------------------------------------------------
// K3: BN stats
// ---------------------------------------------------------------------------
__global__ void stats_kernel(const float* __restrict__ U, const float* __restrict__ V,
                             const float* __restrict__ bias, const int* __restrict__ idx,
                             float* __restrict__ stats) {
    int tid = threadIdx.x;
    int c = tid & 63, kk = tid >> 6;
    int p0 = blockIdx.x * 32;
    float bc = bias[c];
    float sum = 0.f, sumsq = 0.f;
    for (int pp = 0; pp < 32; ++pp) {
        int p = p0 + pp;
        float u = U[(size_t)p * C + c] + bc;
#pragma unroll
        for (int k4 = 0; k4 < 4; ++k4) {
            int j = idx[(size_t)p * KNN + kk * 4 + k4];
            float h = u + V[(size_t)j * C + c];
            sum += h;
            sumsq = fmaf(h, h, sumsq);
        }
    }
    __shared__ float red[2][4][64];
    red[0][kk][c] = sum;
    red[1][kk][c] = sumsq;
    __syncthreads();
    if (tid < 64) {
        float s = red[0][0][tid] + red[0][1][tid] + red[0][2][tid] + red[0][3][tid];
        atomicAdd(&stats[tid], s);
    } else if (tid < 128) {
        int cc = tid - 64;
        float s = red[1][0][cc] + red[1][1][cc] + red[1][2][cc] + red[1][3][cc];
        atomicAdd(&stats[64 + cc], s);
    }
}

__global__ void finalize_kernel(const float* __restrict__ stats,
                                const float* __restrict__ gamma,
                                const float* __restrict__ beta,
                                float* __restrict__ sshift) {
    int c = threadIdx.x;
    const float N = (float)NEDGE;
    float mean = stats[c] / N;
    float var = stats[64 + c] / N - mean * mean;
    float s = gamma[c] * rsqrtf(var + EPSV);
    sshift[c] = s;
    sshift[64 + c] = beta[c] - mean * s;
}

// ---------------------------------------------------------------------------
// K5: out = lrelu(s*(U+b + max/min_k V[idx]) + t)  (monotone fusion of max_k)
// ---------------------------------------------------------------------------
__global__ void out_kernel(const float* __restrict__ U, const float* __restrict__ V,
                           const float* __restrict__ bias, const int* __restrict__ idx,
                           const float* __restrict__ sshift, float* __restrict__ out) {
    int tid = threadIdx.x;
    int c = tid & 63, g = tid >> 6;
    int p0 = blockIdx.x * 16;
    float s = sshift[c], t = sshift[64 + c];
    float bc = bias[c];
    for (int pp = g; pp < 16; pp += 4) {
        int p = p0 + pp;
        float mx = -FLT_MAX, mn = FLT_MAX;
#pragma unroll
        for (int k = 0; k < KNN; ++k) {
            int j = idx[(size_t)p * KNN + k];
            float v = V[(size_t)j * C + c];
            mx = fmaxf(mx, v);
            mn = fminf(mn, v);
        }
        float hsel = (s >= 0.f) ? mx : mn;
        float hn = fmaf(s, U[(size_t)p * C + c] + bc + hsel, t);
        out[(size_t)p * C + c] = (hn >= 0.f) ? hn : SLOPE * hn;
    }
}

// ---------------------------------------------------------------------------
extern "C" void kernel_launch(void* const* d_in, const int* in_sizes, int n_in,
                              void* d_out, int out_size, void* d_ws, size_t ws_size,
                              hipStream_t stream) {
    const float* x     = (const float*)d_in[0];
    const float* W     = (const float*)d_in[2];
    const float* bias  = (const float*)d_in[3];
    const float* gamma = (const float*)d_in[4];
    const float* beta  = (const float*)d_in[5];
    float* out = (float*)d_out;

    float* wsf    = (float*)d_ws;
    float* U      = wsf;
    float* V      = wsf + 2097152;
    uint4* xfh    = (uint4*)wsf;                   // aliases U/V, dead after knn
    uint4* xfm    = (uint4*)(wsf + 1048576);
    uint4* xfl    = (uint4*)(wsf + 2097152);
    float* sq     = wsf + 4194304;
    float* stats  = wsf + 4227072;
    float* sshift = wsf + 4227200;
    int*   idx    = (int*)(wsf + 4227328);
    float* pv     = wsf + 4751616;
    int*   pi     = (int*)(wsf + 6848768);

    hipLaunchKernelGGL(prep_frag, dim3(NPTS / 32), dim3(256), 0, stream, x, xfh, xfm, xfl, sq);
    hipLaunchKernelGGL(knn_kernel, dim3(BATCH * (P / 64) * NQ), dim3(256), 0, stream,
                       (const uint4*)xfh, (const uint4*)xfm, (const uint4*)xfl, sq, pv, pi);
    hipLaunchKernelGGL(merge_kernel, dim3(NPTS / 64), dim3(256), 0, stream, pv, pi, idx);
    hipLaunchKernelGGL(prep_UV, dim3(NPTS / 4), dim3(256), 0, stream, x, W, U, V);
    hipMemsetAsync(stats, 0, 128 * sizeof(float), stream);
    hipLaunchKernelGGL(stats_kernel, dim3(NPTS / 32), dim3(256), 0, stream, U, V, bias, idx, stats);
    hipLaunchKernelGGL(finalize_kernel, dim3(1), dim3(64), 0, stream, stats, gamma, beta, sshift);
    hipLaunchKernelGGL(out_kernel, dim3(NPTS / 16), dim3(256), 0, stream, U, V, bias, idx, sshift, out);
}

// Round 6
// 617.392 us; speedup vs baseline: 1.8040x; 1.2117x over previous
//
#include <hip/hip_runtime.h>
#include <cfloat>

#define BATCH 4
#define P 8192
#define C 64
#define KNN 16
#define NPTS (BATCH * P)        // 32768
#define NEDGE (NPTS * KNN)      // 524288
#define EPSV 1e-5f
#define SLOPE 0.2f
#define NQ 2                    // column-range split per row-tile
#define QCOLS (P / NQ)          // 4096 cols per block

typedef __attribute__((ext_vector_type(8))) short bf16x8;
typedef __attribute__((ext_vector_type(16))) float f32x16;

// ---------------- workspace layout (float element offsets) ----------------
// U      : [NPTS][C]   @ 0          (2097152)   written AFTER knn
// V      : [NPTS][C]   @ 2097152    (2097152)   written AFTER knn
// xfh/xfm/xfl bf16 frags alias U/V region (dead after knn)
// sq     : [NPTS]      @ 4194304    (32768)
// stats  : [128]       @ 4227072
// sshift : [128]       @ 4227200
// idx    : int[NEDGE]  @ 4227328    (524288)
// pv     : [NPTS][NQ][16] float @ 4751616 (1048576)
// pi     : [NPTS][NQ][16] int   @ 5800192 (1048576)
// total = 6848768 floats = 26.1 MB

__device__ __forceinline__ unsigned short f2bf(float f) {
    unsigned u = __float_as_uint(f);
    u += 0x7FFFu + ((u >> 16) & 1u);
    return (unsigned short)(u >> 16);
}
__device__ __forceinline__ float bf2f(unsigned short s) {
    return __uint_as_float(((unsigned)s) << 16);
}

// ---------------------------------------------------------------------------
// K0: fragment-layout 3-way bf16 split of x + exact fp32 row norms.
// xf[(g*4+kk)*64 + lane] (uint4 = 8 bf16) holds point g*32+(lane&31),
// k = kk*16 + (lane>>5)*8 .. +8  — the mfma_f32_32x32x16_bf16 operand map.
// ---------------------------------------------------------------------------
__global__ void prep_frag(const float* __restrict__ x, uint4* __restrict__ xfh,
                          uint4* __restrict__ xfm, uint4* __restrict__ xfl,
                          float* __restrict__ sq) {
    __shared__ float part[32][9];
    int tid = threadIdx.x;
    int ptl = tid >> 3, j8 = tid & 7;
    int g = blockIdx.x;
    int p = g * 32 + ptl;
    const float4* xp = (const float4*)(x + (size_t)p * C + j8 * 8);
    float4 a = xp[0], b = xp[1];
    float v[8] = {a.x, a.y, a.z, a.w, b.x, b.y, b.z, b.w};
    unsigned short hs[8], ms[8], ls[8];
    float ssum = 0.f;
#pragma unroll
    for (int e = 0; e < 8; ++e) {
        float xv = v[e];
        ssum = fmaf(xv, xv, ssum);
        unsigned short h = f2bf(xv);
        float r1 = xv - bf2f(h);
        unsigned short m = f2bf(r1);
        float r2 = r1 - bf2f(m);
        unsigned short l = f2bf(r2);
        hs[e] = h; ms[e] = m; ls[e] = l;
    }
    int dst = (g * 4 + (j8 >> 1)) * 64 + ptl + 32 * (j8 & 1);
    uint4 ph, pm, pl;
    ph.x = (unsigned)hs[0] | ((unsigned)hs[1] << 16);
    ph.y = (unsigned)hs[2] | ((unsigned)hs[3] << 16);
    ph.z = (unsigned)hs[4] | ((unsigned)hs[5] << 16);
    ph.w = (unsigned)hs[6] | ((unsigned)hs[7] << 16);
    pm.x = (unsigned)ms[0] | ((unsigned)ms[1] << 16);
    pm.y = (unsigned)ms[2] | ((unsigned)ms[3] << 16);
    pm.z = (unsigned)ms[4] | ((unsigned)ms[5] << 16);
    pm.w = (unsigned)ms[6] | ((unsigned)ms[7] << 16);
    pl.x = (unsigned)ls[0] | ((unsigned)ls[1] << 16);
    pl.y = (unsigned)ls[2] | ((unsigned)ls[3] << 16);
    pl.z = (unsigned)ls[4] | ((unsigned)ls[5] << 16);
    pl.w = (unsigned)ls[6] | ((unsigned)ls[7] << 16);
    xfh[dst] = ph; xfm[dst] = pm; xfl[dst] = pl;
    part[ptl][j8] = ssum;
    __syncthreads();
    if (j8 == 0) {
        float s = 0.f;
#pragma unroll
        for (int k = 0; k < 8; ++k) s += part[ptl][k];
        sq[p] = s;
    }
}

// ---------------------------------------------------------------------------
// K1: KNN partial, direct-append selection.
// WG = (batch, 64-row tile, column half). 4 waves: wave (wr,wc) computes the
// 32x32 quadrant; survivors (s < row threshold) are appended straight to a
// per-row LDS buffer (64 slots = can never overflow). Wave 0 owns all 64
// rows' top-16 merge. 2 barriers/chunk. No score matrix in LDS at all.
// __launch_bounds__(256,3): unified VGPR/AGPR budget 170/wave — fits the
// 3-split fragments + acc. (256,4)=128 spills (r4), (256,6)=85 disaster (r3).
// ---------------------------------------------------------------------------
__global__ __launch_bounds__(256, 3) void knn_kernel(const uint4* __restrict__ xfh,
                                                     const uint4* __restrict__ xfm,
                                                     const uint4* __restrict__ xfl,
                                                     const float* __restrict__ sq,
                                                     float* __restrict__ pv,
                                                     int* __restrict__ pi) {
    __shared__ float bufv[64 * 65];   // append buffer values, stride 65
    __shared__ int   bufi[64 * 65];   // append buffer ids
    __shared__ int   idL[64 * 17];    // owner top-16 ids
    __shared__ int   cntL[64];
    __shared__ float worstL[64];

    int tid = threadIdx.x;
    int b = blockIdx.x & 3;              // batch -> XCDs {b, b+4}: frags L2-resident
    int t = blockIdx.x >> 2;
    int tile = t & 127;
    int half = t >> 7;
    int bglob = b * P;
    int r0 = tile * 64;
    int colbase = half * QCOLS;
    int w = tid >> 6, lane = tid & 63;
    int wr = w & 1, wc = w >> 1;

    if (tid < 64) { cntL[tid] = 0; worstL[tid] = FLT_MAX; }

    // persistent A fragments for this wave's 32 rows
    int gA = ((bglob + r0) >> 5) + wr;
    bf16x8 Ah[4], Am[4], Al[4];
#pragma unroll
    for (int kk = 0; kk < 4; ++kk) {
        Ah[kk] = __builtin_bit_cast(bf16x8, xfh[(gA * 4 + kk) * 64 + lane]);
        Am[kk] = __builtin_bit_cast(bf16x8, xfm[(gA * 4 + kk) * 64 + lane]);
        Al[kk] = __builtin_bit_cast(bf16x8, xfl[(gA * 4 + kk) * 64 + lane]);
    }

    // wave-0 owner state: lane l owns row l
    float tv[16];
    float worst = FLT_MAX;
#pragma unroll
    for (int j = 0; j < 16; ++j) tv[j] = FLT_MAX;

    int rbase = wr * 32 + 4 * (lane >> 5);   // row of reg: rbase+(reg&3)+8*(reg>>2)
    __syncthreads();

    for (int chunk = 0; chunk < QCOLS / 64; ++chunk) {
        int c0 = colbase + chunk * 64;
        int gB = ((bglob + c0) >> 5) + wc;
        bf16x8 Bh[4], Bm[4], Bl[4];
#pragma unroll
        for (int kk = 0; kk < 4; ++kk) {
            Bh[kk] = __builtin_bit_cast(bf16x8, xfh[(gB * 4 + kk) * 64 + lane]);
            Bm[kk] = __builtin_bit_cast(bf16x8, xfm[(gB * 4 + kk) * 64 + lane]);
            Bl[kk] = __builtin_bit_cast(bf16x8, xfl[(gB * 4 + kk) * 64 + lane]);
        }
        float sc = sq[bglob + c0 + wc * 32 + (lane & 31)];

        // per-reg row thresholds (stale-free: worstL stable since last barrier)
        float tW[16];
#pragma unroll
        for (int reg = 0; reg < 16; ++reg)
            tW[reg] = worstL[rbase + (reg & 3) + 8 * (reg >> 2)];

        f32x16 acc0, acc1;
#pragma unroll
        for (int i = 0; i < 16; ++i) { acc0[i] = 0.f; acc1[i] = 0.f; }
#pragma unroll
        for (int kk = 0; kk < 4; ++kk) {
            acc0 = __builtin_amdgcn_mfma_f32_32x32x16_bf16(Ah[kk], Bh[kk], acc0, 0, 0, 0);
            acc1 = __builtin_amdgcn_mfma_f32_32x32x16_bf16(Ah[kk], Bm[kk], acc1, 0, 0, 0);
            acc0 = __builtin_amdgcn_mfma_f32_32x32x16_bf16(Am[kk], Bh[kk], acc0, 0, 0, 0);
            acc1 = __builtin_amdgcn_mfma_f32_32x32x16_bf16(Am[kk], Bm[kk], acc1, 0, 0, 0);
            acc0 = __builtin_amdgcn_mfma_f32_32x32x16_bf16(Ah[kk], Bl[kk], acc0, 0, 0, 0);
            acc1 = __builtin_amdgcn_mfma_f32_32x32x16_bf16(Al[kk], Bh[kk], acc1, 0, 0, 0);
        }

        int colg = bglob + c0 + wc * 32 + (lane & 31);
#pragma unroll
        for (int reg = 0; reg < 16; ++reg) {
            float s = fmaf(-2.f, acc0[reg] + acc1[reg], sc);
            if (s < tW[reg]) {
                int row = rbase + (reg & 3) + 8 * (reg >> 2);
                int slot = atomicAdd(&cntL[row], 1);   // slot < 64 always
                bufv[row * 65 + slot] = s;
                bufi[row * 65 + slot] = colg;
            }
        }
        __syncthreads();  // (1) appends visible

        if (w == 0) {     // wave 0: lane l merges row l
            int n = cntL[lane];
            for (int k = 0; k < n; ++k) {
                float s = bufv[lane * 65 + k];
                if (s < worst) {
                    // find position of current max
                    float mx = tv[0];
                    int pos = 0;
#pragma unroll
                    for (int j = 1; j < 16; ++j) {
                        bool g = tv[j] > mx;
                        mx = g ? tv[j] : mx;
                        pos = g ? j : pos;
                    }
#pragma unroll
                    for (int j = 0; j < 16; ++j)
                        if (j == pos) tv[j] = s;
                    idL[lane * 17 + pos] = bufi[lane * 65 + k];
                    float nw = fmaxf(fmaxf(fmaxf(tv[0], tv[1]), fmaxf(tv[2], tv[3])),
                                     fmaxf(fmaxf(tv[4], tv[5]), fmaxf(tv[6], tv[7])));
                    nw = fmaxf(nw, fmaxf(fmaxf(fmaxf(tv[8], tv[9]), fmaxf(tv[10], tv[11])),
                                         fmaxf(fmaxf(tv[12], tv[13]), fmaxf(tv[14], tv[15]))));
                    worst = nw;
                }
            }
            if (n > 0) { cntL[lane] = 0; worstL[lane] = worst; }
        }
        __syncthreads();  // (2) merge done: buffers free, worstL stable
    }

    if (w == 0) {
        size_t o = (((size_t)(bglob + r0 + lane)) * NQ + half) * KNN;
#pragma unroll
        for (int j = 0; j < 16; ++j) {
            pv[o + j] = tv[j];
            pi[o + j] = idL[lane * 17 + j];
        }
    }
}

// ---------------------------------------------------------------------------
// K1b: merge NQ=2 partial top-16 lists per row -> final idx.
// 256 threads = 128 rows x 2 halves per block.
// ---------------------------------------------------------------------------
__global__ void merge_kernel(const float* __restrict__ pv, const int* __restrict__ pi,
                             int* __restrict__ idx_out) {
    __shared__ float mv[128 * 33];
    __shared__ int   mi[128 * 33];
    int tid = threadIdx.x;
    int lr = tid & 127, q = tid >> 7;
    int row = blockIdx.x * 128 + lr;
    size_t o = ((size_t)row * NQ + q) * KNN;
#pragma unroll
    for (int j = 0; j < 16; ++j) {
        mv[lr * 33 + q * 16 + j] = pv[o + j];
        mi[lr * 33 + q * 16 + j] = pi[o + j];
    }
    __syncthreads();
    if (tid < 128) {
        float tv[16];
        int ti[16];
        float worst = FLT_MAX;
#pragma unroll
        for (int j = 0; j < 16; ++j) { tv[j] = FLT_MAX; ti[j] = 0; }
        for (int e = 0; e < 32; ++e) {
            float s = mv[tid * 33 + e];
            if (s < worst) {
                float mx = tv[0];
                int pos = 0;
#pragma unroll
                for (int j = 1; j < 16; ++j) {
                    bool g = tv[j] > mx;
                    mx = g ? tv[j] : mx;
                    pos = g ? j : pos;
                }
#pragma unroll
                for (int j = 0; j < 16; ++j)
                    if (j == pos) { tv[j] = s; ti[j] = mi[tid * 33 + e]; }
                float nw = tv[0];
#pragma unroll
                for (int j = 1; j < 16; ++j) nw = fmaxf(nw, tv[j]);
                worst = nw;
            }
        }
        size_t oo = (size_t)row * KNN;
#pragma unroll
        for (int j = 0; j < 16; ++j) idx_out[oo + j] = ti[j];
    }
}

// ---------------------------------------------------------------------------
// K2: U = x @ (W1 - W2), V = x @ W2
// ---------------------------------------------------------------------------
__global__ void prep_UV(const float* __restrict__ x, const float* __restrict__ W,
                        float* __restrict__ U, float* __restrict__ V) {
    __shared__ float Ws[128][64];
    __shared__ float xs[4][64];
    int tid = threadIdx.x;
    for (int i = tid; i < 128 * 64; i += 256) ((float*)Ws)[i] = W[i];
    int p0 = blockIdx.x * 4;
    int r = tid >> 6, c = tid & 63;
    xs[r][c] = x[(size_t)(p0 + r) * C + c];
    __syncthreads();
    float u = 0.f, v = 0.f;
#pragma unroll
    for (int k = 0; k < 64; ++k) {
        float xv = xs[r][k];
        float w1 = Ws[k][c];
        float w2 = Ws[64 + k][c];
        u = fmaf(xv, w1 - w2, u);
        v = fmaf(xv, w2, v);
    }
    size_t o = (size_t)(p0 + r) * C + c;
    U[o] = u;
    V[o] = v;
}

// ---------------------------------------------------------------------------
// K3: BN stats
// ---------------------------------------------------------------------------
__global__ void stats_kernel(const float* __restrict__ U, const float* __restrict__ V,
                             const float* __restrict__ bias, const int* __restrict__ idx,
                             float* __restrict__ stats) {
    int tid = threadIdx.x;
    int c = tid & 63, kk = tid >> 6;
    int p0 = blockIdx.x * 32;
    float bc = bias[c];
    float sum = 0.f, sumsq = 0.f;
    for (int pp = 0; pp < 32; ++pp) {
        int p = p0 + pp;
        float u = U[(size_t)p * C + c] + bc;
#pragma unroll
        for (int k4 = 0; k4 < 4; ++k4) {
            int j = idx[(size_t)p * KNN + kk * 4 + k4];
            float h = u + V[(size_t)j * C + c];
            sum += h;
            sumsq = fmaf(h, h, sumsq);
        }
    }
    __shared__ float red[2][4][64];
    red[0][kk][c] = sum;
    red[1][kk][c] = sumsq;
    __syncthreads();
    if (tid < 64) {
        float s = red[0][0][tid] + red[0][1][tid] + red[0][2][tid] + red[0][3][tid];
        atomicAdd(&stats[tid], s);
    } else if (tid < 128) {
        int cc = tid - 64;
        float s = red[1][0][cc] + red[1][1][cc] + red[1][2][cc] + red[1][3][cc];
        atomicAdd(&stats[64 + cc], s);
    }
}

__global__ void finalize_kernel(const float* __restrict__ stats,
                                const float* __restrict__ gamma,
                                const float* __restrict__ beta,
                                float* __restrict__ sshift) {
    int c = threadIdx.x;
    const float N = (float)NEDGE;
    float mean = stats[c] / N;
    float var = stats[64 + c] / N - mean * mean;
    float s = gamma[c] * rsqrtf(var + EPSV);
    sshift[c] = s;
    sshift[64 + c] = beta[c] - mean * s;
}

// ---------------------------------------------------------------------------
// K5: out = lrelu(s*(U+b + max/min_k V[idx]) + t)  (monotone fusion of max_k)
// ---------------------------------------------------------------------------
__global__ void out_kernel(const float* __restrict__ U, const float* __restrict__ V,
                           const float* __restrict__ bias, const int* __restrict__ idx,
                           const float* __restrict__ sshift, float* __restrict__ out) {
    int tid = threadIdx.x;
    int c = tid & 63, g = tid >> 6;
    int p0 = blockIdx.x * 16;
    float s = sshift[c], t = sshift[64 + c];
    float bc = bias[c];
    for (int pp = g; pp < 16; pp += 4) {
        int p = p0 + pp;
        float mx = -FLT_MAX, mn = FLT_MAX;
#pragma unroll
        for (int k = 0; k < KNN; ++k) {
            int j = idx[(size_t)p * KNN + k];
            float v = V[(size_t)j * C + c];
            mx = fmaxf(mx, v);
            mn = fminf(mn, v);
        }
        float hsel = (s >= 0.f) ? mx : mn;
        float hn = fmaf(s, U[(size_t)p * C + c] + bc + hsel, t);
        out[(size_t)p * C + c] = (hn >= 0.f) ? hn : SLOPE * hn;
    }
}

// ---------------------------------------------------------------------------
extern "C" void kernel_launch(void* const* d_in, const int* in_sizes, int n_in,
                              void* d_out, int out_size, void* d_ws, size_t ws_size,
                              hipStream_t stream) {
    const float* x     = (const float*)d_in[0];
    const float* W     = (const float*)d_in[2];
    const float* bias  = (const float*)d_in[3];
    const float* gamma = (const float*)d_in[4];
    const float* beta  = (const float*)d_in[5];
    float* out = (float*)d_out;

    float* wsf    = (float*)d_ws;
    float* U      = wsf;
    float* V      = wsf + 2097152;
    uint4* xfh    = (uint4*)wsf;                   // aliases U/V, dead after knn
    uint4* xfm    = (uint4*)(wsf + 1048576);
    uint4* xfl    = (uint4*)(wsf + 2097152);
    float* sq     = wsf + 4194304;
    float* stats  = wsf + 4227072;
    float* sshift = wsf + 4227200;
    int*   idx    = (int*)(wsf + 4227328);
    float* pv     = wsf + 4751616;
    int*   pi     = (int*)(wsf + 5800192);

    hipLaunchKernelGGL(prep_frag, dim3(NPTS / 32), dim3(256), 0, stream, x, xfh, xfm, xfl, sq);
    hipLaunchKernelGGL(knn_kernel, dim3(BATCH * (P / 64) * NQ), dim3(256), 0, stream,
                       (const uint4*)xfh, (const uint4*)xfm, (const uint4*)xfl, sq, pv, pi);
    hipLaunchKernelGGL(merge_kernel, dim3(NPTS / 128), dim3(256), 0, stream, pv, pi, idx);
    hipLaunchKernelGGL(prep_UV, dim3(NPTS / 4), dim3(256), 0, stream, x, W, U, V);
    hipMemsetAsync(stats, 0, 128 * sizeof(float), stream);
    hipLaunchKernelGGL(stats_kernel, dim3(NPTS / 32), dim3(256), 0, stream, U, V, bias, idx, stats);
    hipLaunchKernelGGL(finalize_kernel, dim3(1), dim3(64), 0, stream, stats, gamma, beta, sshift);
    hipLaunchKernelGGL(out_kernel, dim3(NPTS / 16), dim3(256), 0, stream, U, V, bias, idx, sshift, out);
}

// Round 7
// 571.272 us; speedup vs baseline: 1.9496x; 1.0807x over previous
//
#include <hip/hip_runtime.h>
#include <cfloat>

#define BATCH 4
#define P 8192
#define C 64
#define KNN 16
#define NPTS (BATCH * P)        // 32768
#define NEDGE (NPTS * KNN)      // 524288
#define EPSV 1e-5f
#define SLOPE 0.2f
#define NQ 2                    // column-range split per row-tile
#define QCOLS (P / NQ)          // 4096 cols per block

typedef __attribute__((ext_vector_type(8))) short bf16x8;
typedef __attribute__((ext_vector_type(16))) float f32x16;

// ---------------- workspace layout (float element offsets) ----------------
// U      : [NPTS][C]   @ 0          (2097152)   written AFTER knn
// V      : [NPTS][C]   @ 2097152    (2097152)   written AFTER knn
// xfh/xfm/xfl bf16 frags alias U/V region (dead after knn)
// sq     : [NPTS]      @ 4194304    (32768)
// stats  : [128]       @ 4227072
// sshift : [128]       @ 4227200
// idx    : int[NEDGE]  @ 4227328    (524288)
// pv     : [NPTS][NQ][16] float @ 4751616 (1048576)
// pi     : [NPTS][NQ][16] int   @ 5800192 (1048576)
// total = 6848768 floats = 26.1 MB

__device__ __forceinline__ unsigned short f2bf(float f) {
    unsigned u = __float_as_uint(f);
    u += 0x7FFFu + ((u >> 16) & 1u);
    return (unsigned short)(u >> 16);
}
__device__ __forceinline__ float bf2f(unsigned short s) {
    return __uint_as_float(((unsigned)s) << 16);
}

// ---------------------------------------------------------------------------
// K0: fragment-layout 3-way bf16 split of x + exact fp32 row norms.
// xf[(g*4+kk)*64 + lane] (uint4 = 8 bf16) holds point g*32+(lane&31),
// k = kk*16 + (lane>>5)*8 .. +8  — the mfma_f32_32x32x16_bf16 operand map.
// ---------------------------------------------------------------------------
__global__ void prep_frag(const float* __restrict__ x, uint4* __restrict__ xfh,
                          uint4* __restrict__ xfm, uint4* __restrict__ xfl,
                          float* __restrict__ sq) {
    __shared__ float part[32][9];
    int tid = threadIdx.x;
    int ptl = tid >> 3, j8 = tid & 7;
    int g = blockIdx.x;
    int p = g * 32 + ptl;
    const float4* xp = (const float4*)(x + (size_t)p * C + j8 * 8);
    float4 a = xp[0], b = xp[1];
    float v[8] = {a.x, a.y, a.z, a.w, b.x, b.y, b.z, b.w};
    unsigned short hs[8], ms[8], ls[8];
    float ssum = 0.f;
#pragma unroll
    for (int e = 0; e < 8; ++e) {
        float xv = v[e];
        ssum = fmaf(xv, xv, ssum);
        unsigned short h = f2bf(xv);
        float r1 = xv - bf2f(h);
        unsigned short m = f2bf(r1);
        float r2 = r1 - bf2f(m);
        unsigned short l = f2bf(r2);
        hs[e] = h; ms[e] = m; ls[e] = l;
    }
    int dst = (g * 4 + (j8 >> 1)) * 64 + ptl + 32 * (j8 & 1);
    uint4 ph, pm, pl;
    ph.x = (unsigned)hs[0] | ((unsigned)hs[1] << 16);
    ph.y = (unsigned)hs[2] | ((unsigned)hs[3] << 16);
    ph.z = (unsigned)hs[4] | ((unsigned)hs[5] << 16);
    ph.w = (unsigned)hs[6] | ((unsigned)hs[7] << 16);
    pm.x = (unsigned)ms[0] | ((unsigned)ms[1] << 16);
    pm.y = (unsigned)ms[2] | ((unsigned)ms[3] << 16);
    pm.z = (unsigned)ms[4] | ((unsigned)ms[5] << 16);
    pm.w = (unsigned)ms[6] | ((unsigned)ms[7] << 16);
    pl.x = (unsigned)ls[0] | ((unsigned)ls[1] << 16);
    pl.y = (unsigned)ls[2] | ((unsigned)ls[3] << 16);
    pl.z = (unsigned)ls[4] | ((unsigned)ls[5] << 16);
    pl.w = (unsigned)ls[6] | ((unsigned)ls[7] << 16);
    xfh[dst] = ph; xfm[dst] = pm; xfl[dst] = pl;
    part[ptl][j8] = ssum;
    __syncthreads();
    if (j8 == 0) {
        float s = 0.f;
#pragma unroll
        for (int k = 0; k < 8; ++k) s += part[ptl][k];
        sq[p] = s;
    }
}

// ---------------------------------------------------------------------------
// K1: KNN partial, direct-append selection + distributed merge.
// WG = (batch, 64-row tile, column half). Wave (wr,wc) computes a 32x32
// quadrant. Survivors append to per-row LDS buffers (64 slots, can't
// overflow). Chunk 0 (everything survives) writes slotted — NO atomics —
// ids reconstructed in the merge (kills the 32-way atomic serialization
// that dominated SQ_LDS_BANK_CONFLICT in r6). Merge is distributed:
// wave w, lanes 0-15 own rows 16w..16w+15 (r6's wave-0-only merge idled
// 3 waves). 2 barriers/chunk.
// __launch_bounds__(256,4): unified budget 128/wave; r6 footprint ~112
// (80 VGPR + 32 AGPR). r4's spill at (256,4) was the old heavier kernel.
// ---------------------------------------------------------------------------
__global__ __launch_bounds__(256, 4) void knn_kernel(const uint4* __restrict__ xfh,
                                                     const uint4* __restrict__ xfm,
                                                     const uint4* __restrict__ xfl,
                                                     const float* __restrict__ sq,
                                                     float* __restrict__ pv,
                                                     int* __restrict__ pi) {
    __shared__ float bufv[64 * 65];   // append buffer values
    __shared__ int   bufi[64 * 65];   // append buffer ids (chunks >= 1 only)
    __shared__ int   idL[64 * 17];    // owner top-16 ids
    __shared__ int   cntL[64];
    __shared__ float worstL[64];

    int tid = threadIdx.x;
    int b = blockIdx.x & 3;              // batch -> XCDs {b, b+4}: frags L2-resident
    int t = blockIdx.x >> 2;
    int tile = t & 127;
    int half = t >> 7;
    int bglob = b * P;
    int r0 = tile * 64;
    int colbase = half * QCOLS;
    int w = tid >> 6, lane = tid & 63;
    int wr = w & 1, wc = w >> 1;

    if (tid < 64) { cntL[tid] = 0; worstL[tid] = FLT_MAX; }

    // persistent A fragments for this wave's 32 rows
    int gA = ((bglob + r0) >> 5) + wr;
    bf16x8 Ah[4], Am[4], Al[4];
#pragma unroll
    for (int kk = 0; kk < 4; ++kk) {
        Ah[kk] = __builtin_bit_cast(bf16x8, xfh[(gA * 4 + kk) * 64 + lane]);
        Am[kk] = __builtin_bit_cast(bf16x8, xfm[(gA * 4 + kk) * 64 + lane]);
        Al[kk] = __builtin_bit_cast(bf16x8, xfl[(gA * 4 + kk) * 64 + lane]);
    }

    // distributed owner state: wave w, lane<16 owns row w*16+lane
    float tv[16];
    float worst = FLT_MAX;
#pragma unroll
    for (int j = 0; j < 16; ++j) tv[j] = FLT_MAX;
    int rown = w * 16 + (lane & 15);
    bool owner = (lane < 16);

    int rbase = wr * 32 + 4 * (lane >> 5);   // row of reg: rbase+(reg&3)+8*(reg>>2)
    int colq = wc * 32 + (lane & 31);        // this lane's column within chunk
    __syncthreads();

    for (int chunk = 0; chunk < QCOLS / 64; ++chunk) {
        int c0 = colbase + chunk * 64;
        int gB = ((bglob + c0) >> 5) + wc;
        bf16x8 Bh[4], Bm[4], Bl[4];
#pragma unroll
        for (int kk = 0; kk < 4; ++kk) {
            Bh[kk] = __builtin_bit_cast(bf16x8, xfh[(gB * 4 + kk) * 64 + lane]);
            Bm[kk] = __builtin_bit_cast(bf16x8, xfm[(gB * 4 + kk) * 64 + lane]);
            Bl[kk] = __builtin_bit_cast(bf16x8, xfl[(gB * 4 + kk) * 64 + lane]);
        }
        float sc = sq[bglob + c0 + colq];

        f32x16 acc0, acc1;
#pragma unroll
        for (int i = 0; i < 16; ++i) { acc0[i] = 0.f; acc1[i] = 0.f; }
#pragma unroll
        for (int kk = 0; kk < 4; ++kk) {
            acc0 = __builtin_amdgcn_mfma_f32_32x32x16_bf16(Ah[kk], Bh[kk], acc0, 0, 0, 0);
            acc1 = __builtin_amdgcn_mfma_f32_32x32x16_bf16(Ah[kk], Bm[kk], acc1, 0, 0, 0);
            acc0 = __builtin_amdgcn_mfma_f32_32x32x16_bf16(Am[kk], Bh[kk], acc0, 0, 0, 0);
            acc1 = __builtin_amdgcn_mfma_f32_32x32x16_bf16(Am[kk], Bm[kk], acc1, 0, 0, 0);
            acc0 = __builtin_amdgcn_mfma_f32_32x32x16_bf16(Ah[kk], Bl[kk], acc0, 0, 0, 0);
            acc1 = __builtin_amdgcn_mfma_f32_32x32x16_bf16(Al[kk], Bh[kk], acc1, 0, 0, 0);
        }

        if (chunk == 0) {
            // flood phase: every score survives; write to its natural slot,
            // no atomics, conflict-free (2-way lane aliasing only).
#pragma unroll
            for (int reg = 0; reg < 16; ++reg) {
                float s = fmaf(-2.f, acc0[reg] + acc1[reg], sc);
                int row = rbase + (reg & 3) + 8 * (reg >> 2);
                bufv[row * 65 + colq] = s;
            }
        } else {
            // per-reg row thresholds: 4x ds_read_b128 from worstL
            float4 twA[4];
#pragma unroll
            for (int g4 = 0; g4 < 4; ++g4)
                twA[g4] = *(const float4*)&worstL[rbase + 8 * g4];
            int colg = bglob + c0 + colq;
#pragma unroll
            for (int reg = 0; reg < 16; ++reg) {
                float s = fmaf(-2.f, acc0[reg] + acc1[reg], sc);
                float tW = ((const float*)&twA[reg >> 2])[reg & 3];
                if (s < tW) {
                    int row = rbase + (reg & 3) + 8 * (reg >> 2);
                    int slot = atomicAdd(&cntL[row], 1);   // slot < 64 always
                    bufv[row * 65 + slot] = s;
                    bufi[row * 65 + slot] = colg;
                }
            }
        }
        __syncthreads();  // (1) appends visible

        if (owner) {      // wave w, lane l<16 merges row 16w+l
            int n = (chunk == 0) ? 64 : cntL[rown];
            for (int k = 0; k < n; ++k) {
                float s = bufv[rown * 65 + k];
                if (s < worst) {
                    float mx = tv[0];
                    int pos = 0;
#pragma unroll
                    for (int j = 1; j < 16; ++j) {
                        bool g = tv[j] > mx;
                        mx = g ? tv[j] : mx;
                        pos = g ? j : pos;
                    }
#pragma unroll
                    for (int j = 0; j < 16; ++j)
                        if (j == pos) tv[j] = s;
                    idL[rown * 17 + pos] = (chunk == 0) ? (bglob + colbase + k)
                                                        : bufi[rown * 65 + k];
                    float nw = fmaxf(fmaxf(fmaxf(tv[0], tv[1]), fmaxf(tv[2], tv[3])),
                                     fmaxf(fmaxf(tv[4], tv[5]), fmaxf(tv[6], tv[7])));
                    nw = fmaxf(nw, fmaxf(fmaxf(fmaxf(tv[8], tv[9]), fmaxf(tv[10], tv[11])),
                                         fmaxf(fmaxf(tv[12], tv[13]), fmaxf(tv[14], tv[15]))));
                    worst = nw;
                }
            }
            cntL[rown] = 0;
            worstL[rown] = worst;
        }
        __syncthreads();  // (2) merge done: buffers free, worstL stable
    }

    if (owner) {
        size_t o = (((size_t)(bglob + r0 + rown)) * NQ + half) * KNN;
#pragma unroll
        for (int j = 0; j < 16; ++j) {
            pv[o + j] = tv[j];
            pi[o + j] = idL[rown * 17 + j];
        }
    }
}

// ---------------------------------------------------------------------------
// K1b: merge NQ=2 partial top-16 lists per row -> final idx.
// 256 threads = 128 rows x 2 halves per block.
// ---------------------------------------------------------------------------
__global__ void merge_kernel(const float* __restrict__ pv, const int* __restrict__ pi,
                             int* __restrict__ idx_out) {
    __shared__ float mv[128 * 33];
    __shared__ int   mi[128 * 33];
    int tid = threadIdx.x;
    int lr = tid & 127, q = tid >> 7;
    int row = blockIdx.x * 128 + lr;
    size_t o = ((size_t)row * NQ + q) * KNN;
#pragma unroll
    for (int j = 0; j < 16; ++j) {
        mv[lr * 33 + q * 16 + j] = pv[o + j];
        mi[lr * 33 + q * 16 + j] = pi[o + j];
    }
    __syncthreads();
    if (tid < 128) {
        float tv[16];
        int ti[16];
        float worst = FLT_MAX;
#pragma unroll
        for (int j = 0; j < 16; ++j) { tv[j] = FLT_MAX; ti[j] = 0; }
        for (int e = 0; e < 32; ++e) {
            float s = mv[tid * 33 + e];
            if (s < worst) {
                float mx = tv[0];
                int pos = 0;
#pragma unroll
                for (int j = 1; j < 16; ++j) {
                    bool g = tv[j] > mx;
                    mx = g ? tv[j] : mx;
                    pos = g ? j : pos;
                }
#pragma unroll
                for (int j = 0; j < 16; ++j)
                    if (j == pos) { tv[j] = s; ti[j] = mi[tid * 33 + e]; }
                float nw = tv[0];
#pragma unroll
                for (int j = 1; j < 16; ++j) nw = fmaxf(nw, tv[j]);
                worst = nw;
            }
        }
        size_t oo = (size_t)row * KNN;
#pragma unroll
        for (int j = 0; j < 16; ++j) idx_out[oo + j] = ti[j];
    }
}

// ---------------------------------------------------------------------------
// K2: U = x @ (W1 - W2), V = x @ W2
// ---------------------------------------------------------------------------
__global__ void prep_UV(const float* __restrict__ x, const float* __restrict__ W,
                        float* __restrict__ U, float* __restrict__ V) {
    __shared__ float Ws[128][64];
    __shared__ float xs[4][64];
    int tid = threadIdx.x;
    for (int i = tid; i < 128 * 64; i += 256) ((float*)Ws)[i] = W[i];
    int p0 = blockIdx.x * 4;
    int r = tid >> 6, c = tid & 63;
    xs[r][c] = x[(size_t)(p0 + r) * C + c];
    __syncthreads();
    float u = 0.f, v = 0.f;
#pragma unroll
    for (int k = 0; k < 64; ++k) {
        float xv = xs[r][k];
        float w1 = Ws[k][c];
        float w2 = Ws[64 + k][c];
        u = fmaf(xv, w1 - w2, u);
        v = fmaf(xv, w2, v);
    }
    size_t o = (size_t)(p0 + r) * C + c;
    U[o] = u;
    V[o] = v;
}

// ---------------------------------------------------------------------------
// K3: BN stats
// ---------------------------------------------------------------------------
__global__ void stats_kernel(const float* __restrict__ U, const float* __restrict__ V,
                             const float* __restrict__ bias, const int* __restrict__ idx,
                             float* __restrict__ stats) {
    int tid = threadIdx.x;
    int c = tid & 63, kk = tid >> 6;
    int p0 = blockIdx.x * 32;
    float bc = bias[c];
    float sum = 0.f, sumsq = 0.f;
    for (int pp = 0; pp < 32; ++pp) {
        int p = p0 + pp;
        float u = U[(size_t)p * C + c] + bc;
#pragma unroll
        for (int k4 = 0; k4 < 4; ++k4) {
            int j = idx[(size_t)p * KNN + kk * 4 + k4];
            float h = u + V[(size_t)j * C + c];
            sum += h;
            sumsq = fmaf(h, h, sumsq);
        }
    }
    __shared__ float red[2][4][64];
    red[0][kk][c] = sum;
    red[1][kk][c] = sumsq;
    __syncthreads();
    if (tid < 64) {
        float s = red[0][0][tid] + red[0][1][tid] + red[0][2][tid] + red[0][3][tid];
        atomicAdd(&stats[tid], s);
    } else if (tid < 128) {
        int cc = tid - 64;
        float s = red[1][0][cc] + red[1][1][cc] + red[1][2][cc] + red[1][3][cc];
        atomicAdd(&stats[64 + cc], s);
    }
}

__global__ void finalize_kernel(const float* __restrict__ stats,
                                const float* __restrict__ gamma,
                                const float* __restrict__ beta,
                                float* __restrict__ sshift) {
    int c = threadIdx.x;
    const float N = (float)NEDGE;
    float mean = stats[c] / N;
    float var = stats[64 + c] / N - mean * mean;
    float s = gamma[c] * rsqrtf(var + EPSV);
    sshift[c] = s;
    sshift[64 + c] = beta[c] - mean * s;
}

// ---------------------------------------------------------------------------
// K5: out = lrelu(s*(U+b + max/min_k V[idx]) + t)  (monotone fusion of max_k)
// ---------------------------------------------------------------------------
__global__ void out_kernel(const float* __restrict__ U, const float* __restrict__ V,
                           const float* __restrict__ bias, const int* __restrict__ idx,
                           const float* __restrict__ sshift, float* __restrict__ out) {
    int tid = threadIdx.x;
    int c = tid & 63, g = tid >> 6;
    int p0 = blockIdx.x * 16;
    float s = sshift[c], t = sshift[64 + c];
    float bc = bias[c];
    for (int pp = g; pp < 16; pp += 4) {
        int p = p0 + pp;
        float mx = -FLT_MAX, mn = FLT_MAX;
#pragma unroll
        for (int k = 0; k < KNN; ++k) {
            int j = idx[(size_t)p * KNN + k];
            float v = V[(size_t)j * C + c];
            mx = fmaxf(mx, v);
            mn = fminf(mn, v);
        }
        float hsel = (s >= 0.f) ? mx : mn;
        float hn = fmaf(s, U[(size_t)p * C + c] + bc + hsel, t);
        out[(size_t)p * C + c] = (hn >= 0.f) ? hn : SLOPE * hn;
    }
}

// ---------------------------------------------------------------------------
extern "C" void kernel_launch(void* const* d_in, const int* in_sizes, int n_in,
                              void* d_out, int out_size, void* d_ws, size_t ws_size,
                              hipStream_t stream) {
    const float* x     = (const float*)d_in[0];
    const float* W     = (const float*)d_in[2];
    const float* bias  = (const float*)d_in[3];
    const float* gamma = (const float*)d_in[4];
    const float* beta  = (const float*)d_in[5];
    float* out = (float*)d_out;

    float* wsf    = (float*)d_ws;
    float* U      = wsf;
    float* V      = wsf + 2097152;
    uint4* xfh    = (uint4*)wsf;                   // aliases U/V, dead after knn
    uint4* xfm    = (uint4*)(wsf + 1048576);
    uint4* xfl    = (uint4*)(wsf + 2097152);
    float* sq     = wsf + 4194304;
    float* stats  = wsf + 4227072;
    float* sshift = wsf + 4227200;
    int*   idx    = (int*)(wsf + 4227328);
    float* pv     = wsf + 4751616;
    int*   pi     = (int*)(wsf + 5800192);

    hipLaunchKernelGGL(prep_frag, dim3(NPTS / 32), dim3(256), 0, stream, x, xfh, xfm, xfl, sq);
    hipLaunchKernelGGL(knn_kernel, dim3(BATCH * (P / 64) * NQ), dim3(256), 0, stream,
                       (const uint4*)xfh, (const uint4*)xfm, (const uint4*)xfl, sq, pv, pi);
    hipLaunchKernelGGL(merge_kernel, dim3(NPTS / 128), dim3(256), 0, stream, pv, pi, idx);
    hipLaunchKernelGGL(prep_UV, dim3(NPTS / 4), dim3(256), 0, stream, x, W, U, V);
    hipMemsetAsync(stats, 0, 128 * sizeof(float), stream);
    hipLaunchKernelGGL(stats_kernel, dim3(NPTS / 32), dim3(256), 0, stream, U, V, bias, idx, stats);
    hipLaunchKernelGGL(finalize_kernel, dim3(1), dim3(64), 0, stream, stats, gamma, beta, sshift);
    hipLaunchKernelGGL(out_kernel, dim3(NPTS / 16), dim3(256), 0, stream, U, V, bias, idx, sshift, out);
}